// Round 8
// baseline (1991.669 us; speedup 1.0000x reference)
//
#include <hip/hip_runtime.h>

typedef _Float16 f16x8 __attribute__((ext_vector_type(8)));
typedef float f32x4 __attribute__((ext_vector_type(4)));

#define BB 16
#define TT 4096
#define DD 128
#define HH 256

__device__ __forceinline__ float tanh_fast(float x) {
    // tanh(x) = 1 - 2/(exp(2x)+1); exact at both saturations
    float e = __expf(2.0f * x);
    return 1.0f - 2.0f * __builtin_amdgcn_rcpf(e + 1.0f);
}

// ---------------- Phase 1: xh[b,t,h] = sum_d X[b,t,d]*W_x[h,d] + b_x[h] -----
__global__ __launch_bounds__(256) void x2h_gemm(
    const float* __restrict__ inp, const float* __restrict__ Wx,
    const float* __restrict__ bx, float* __restrict__ out)
{
    const int tid = threadIdx.x;
    const int ty = tid >> 4, tx = tid & 15;
    const int row0 = blockIdx.x * 128 + ty * 8;   // flattened (b,t)
    const int col0 = blockIdx.y * 128 + tx * 8;   // h

    float acc[8][8] = {};

    #pragma unroll 2
    for (int k4 = 0; k4 < DD / 4; ++k4) {
        float4 a[8], b[8];
        #pragma unroll
        for (int r = 0; r < 8; ++r)
            a[r] = *(const float4*)&inp[(size_t)(row0 + r) * DD + k4 * 4];
        #pragma unroll
        for (int c = 0; c < 8; ++c)
            b[c] = *(const float4*)&Wx[(size_t)(col0 + c) * DD + k4 * 4];
        #pragma unroll
        for (int r = 0; r < 8; ++r)
            #pragma unroll
            for (int c = 0; c < 8; ++c)
                acc[r][c] += a[r].x * b[c].x + a[r].y * b[c].y
                           + a[r].z * b[c].z + a[r].w * b[c].w;
    }

    float4 bx0 = *(const float4*)&bx[col0];
    float4 bx1 = *(const float4*)&bx[col0 + 4];
    #pragma unroll
    for (int r = 0; r < 8; ++r) {
        float4 o0, o1;
        o0.x = acc[r][0] + bx0.x; o0.y = acc[r][1] + bx0.y;
        o0.z = acc[r][2] + bx0.z; o0.w = acc[r][3] + bx0.w;
        o1.x = acc[r][4] + bx1.x; o1.y = acc[r][5] + bx1.y;
        o1.z = acc[r][6] + bx1.z; o1.w = acc[r][7] + bx1.w;
        *(float4*)&out[(size_t)(row0 + r) * HH + col0]     = o0;
        *(float4*)&out[(size_t)(row0 + r) * HH + col0 + 4] = o1;
    }
}

// ---------------- Phase 2: MFMA scan, 512 threads (8 waves) per batch -------
// K-split MFMA: wave w = (nq=w>>1 N-quarter, kh=w&1 K-half) computes partial
// matvec for outputs [64nq,64nq+64) over k in [128kh,128kh+128):
// 4 N-tiles x 4 K-tiles = 16 MFMA/wave/step (per-SIMD pipe: 2 waves x 16 x
// ~19.4cyc ~ 620 cyc -- the floor; 2 waves/SIMD hide ds_read/tanh/barrier
// latency that R7's single wave ate serially). A-reads stay 4/wave = 32/CU
// (N-split at 8 waves would need 64 -> LDS-pipe-bound). Partials exchanged
// through a [2][256] f32 LDS plane; threads 0-255 reduce+tanh+publish.
// All new LDS ops are stride-4/stride-2 -> <=2-way bank aliasing (free).
__global__ __launch_bounds__(512, 2) void rnn_scan(
    const float* __restrict__ Wh, const float* __restrict__ bh,
    float* __restrict__ out)
{
    const int tid  = threadIdx.x;       // 0..511
    const int w    = tid >> 6;          // wave 0..7
    const int lane = tid & 63;
    const int g    = lane >> 4;         // k-subgroup / row-group 0..3
    const int c    = lane & 15;         // col within tile
    const int kh   = w & 1;             // K-half 0..1
    const int nq   = w >> 1;            // N-quarter 0..3
    const int b    = blockIdx.x;        // batch

    __shared__ __align__(16) _Float16 hbuf[2][HH];
    __shared__ __align__(16) float     part[2][HH];

    // B-fragments, resident in (A)GPRs for the whole scan:
    // wb[T][t] = W[64nq+16T+c][128kh+32t+8g .. +7] as 8 halfs
    f16x8 wb[4][4];
    #pragma unroll
    for (int T = 0; T < 4; ++T) {
        const float* wrow = Wh + (size_t)((nq << 6) + (T << 4) + c) * HH + (kh << 7);
        #pragma unroll
        for (int t = 0; t < 4; ++t) {
            const float* wp = wrow + (t << 5) + (g << 3);
            float4 v0 = *(const float4*)wp;
            float4 v1 = *(const float4*)(wp + 4);
            wb[T][t] = f16x8{(_Float16)v0.x, (_Float16)v0.y,
                             (_Float16)v0.z, (_Float16)v0.w,
                             (_Float16)v1.x, (_Float16)v1.y,
                             (_Float16)v1.z, (_Float16)v1.w};
        }
    }

    const int jp = (nq << 6) + (g << 4) + c;   // partial slot: 64 distinct/wave

    float bhv = 0.f;
    float* colp = nullptr;
    if (tid < HH) {
        bhv  = bh[tid];
        colp = out + (size_t)b * TT * HH + tid;   // xh column tid, stride HH
        hbuf[0][tid] = (_Float16)0.f;
    }

    constexpr int CH = 8;                          // x prefetch chunk
    float xc[CH], xn[CH];
    if (tid < HH) {
        #pragma unroll
        for (int i = 0; i < CH; ++i) xc[i] = colp[(size_t)i * HH];
    }
    __syncthreads();   // zeros visible

    // A-frag byte base: K-tiles 4kh..4kh+3, this lane's 16B sub-slot
    const int abase = (kh << 8) + (g << 4);

    int cur = 0;
    const int NC = TT / CH;
    for (int cch = 0; cch < NC; ++cch) {
        if (tid < HH && cch + 1 < NC) {
            const float* p = colp + (size_t)(cch + 1) * CH * HH;
            #pragma unroll
            for (int i = 0; i < CH; ++i) xn[i] = p[(size_t)i * HH];
        }
        float* op = colp + (size_t)cch * CH * HH;   // valid only when tid<HH
        #pragma unroll
        for (int s = 0; s < CH; ++s) {
            const char* hb = (const char*)hbuf[cur];
            uint4 hv0 = *(const uint4*)(hb + abase + 0 * 64);
            uint4 hv1 = *(const uint4*)(hb + abase + 1 * 64);
            uint4 hv2 = *(const uint4*)(hb + abase + 2 * 64);
            uint4 hv3 = *(const uint4*)(hb + abase + 3 * 64);
            f16x8 a0 = __builtin_bit_cast(f16x8, hv0);
            f16x8 a1 = __builtin_bit_cast(f16x8, hv1);
            f16x8 a2 = __builtin_bit_cast(f16x8, hv2);
            f16x8 a3 = __builtin_bit_cast(f16x8, hv3);

            f32x4 acc0 = {0.f, 0.f, 0.f, 0.f};
            f32x4 acc1 = {0.f, 0.f, 0.f, 0.f};
            f32x4 acc2 = {0.f, 0.f, 0.f, 0.f};
            f32x4 acc3 = {0.f, 0.f, 0.f, 0.f};
#define MF(ACC, T, AV, TI) \
            ACC = __builtin_amdgcn_mfma_f32_16x16x32_f16(AV, wb[T][TI], ACC, 0, 0, 0);
            MF(acc0, 0, a0, 0) MF(acc1, 1, a0, 0) MF(acc2, 2, a0, 0) MF(acc3, 3, a0, 0)
            MF(acc0, 0, a1, 1) MF(acc1, 1, a1, 1) MF(acc2, 2, a1, 1) MF(acc3, 3, a1, 1)
            MF(acc0, 0, a2, 2) MF(acc1, 1, a2, 2) MF(acc2, 2, a2, 2) MF(acc3, 3, a2, 2)
            MF(acc0, 0, a3, 3) MF(acc1, 1, a3, 3) MF(acc2, 2, a3, 3) MF(acc3, 3, a3, 3)
#undef MF
            // lane publishes partial for output (nq, tile g, col c); all C
            // rows identical -> element 0, select acc by g (3 cndmask)
            float v = acc0[0];
            v = (g == 1) ? acc1[0] : v;
            v = (g == 2) ? acc2[0] : v;
            v = (g == 3) ? acc3[0] : v;
            part[kh][jp] = v;
            __syncthreads();

            if (tid < HH) {
                float z  = xc[s] + bhv + part[0][tid] + part[1][tid];
                float hn = tanh_fast(z);
                op[(size_t)s * HH] = hn;              // overwrite xh with h
                hbuf[cur ^ 1][tid] = (_Float16)hn;    // publish for next step
            }
            cur ^= 1;
            __syncthreads();
        }
        if (tid < HH) {
            #pragma unroll
            for (int i = 0; i < CH; ++i) xc[i] = xn[i];
        }
    }
}

extern "C" void kernel_launch(void* const* d_in, const int* in_sizes, int n_in,
                              void* d_out, int out_size, void* d_ws, size_t ws_size,
                              hipStream_t stream) {
    const float* inp = (const float*)d_in[0];   // [B,T,D]
    const float* Wx  = (const float*)d_in[1];   // [H,D]
    const float* bx  = (const float*)d_in[2];   // [H]
    const float* Wh  = (const float*)d_in[3];   // [H,H]
    const float* bh  = (const float*)d_in[4];   // [H]
    float* out = (float*)d_out;                 // [B,T,H]

    dim3 g1(BB * TT / 128, HH / 128);
    x2h_gemm<<<g1, 256, 0, stream>>>(inp, Wx, bx, out);
    rnn_scan<<<BB, 512, 0, stream>>>(Wh, bh, out);
}

// Round 10
// 1906.411 us; speedup vs baseline: 1.0447x; 1.0447x over previous
//
#include <hip/hip_runtime.h>

typedef _Float16 f16x8 __attribute__((ext_vector_type(8)));
typedef float f32x4 __attribute__((ext_vector_type(4)));

#define BB 16
#define TT 4096
#define DD 128
#define HH 256

__device__ __forceinline__ float tanh_fast(float x) {
    // tanh(x) = 1 - 2/(exp(2x)+1); exact at both saturations
    float e = __expf(2.0f * x);
    return 1.0f - 2.0f * __builtin_amdgcn_rcpf(e + 1.0f);
}

// ---------------- Phase 1: xh[b,t,h] = sum_d X[b,t,d]*W_x[h,d] + b_x[h] -----
__global__ __launch_bounds__(256) void x2h_gemm(
    const float* __restrict__ inp, const float* __restrict__ Wx,
    const float* __restrict__ bx, float* __restrict__ out)
{
    const int tid = threadIdx.x;
    const int ty = tid >> 4, tx = tid & 15;
    const int row0 = blockIdx.x * 128 + ty * 8;   // flattened (b,t)
    const int col0 = blockIdx.y * 128 + tx * 8;   // h

    float acc[8][8] = {};

    #pragma unroll 2
    for (int k4 = 0; k4 < DD / 4; ++k4) {
        float4 a[8], b[8];
        #pragma unroll
        for (int r = 0; r < 8; ++r)
            a[r] = *(const float4*)&inp[(size_t)(row0 + r) * DD + k4 * 4];
        #pragma unroll
        for (int c = 0; c < 8; ++c)
            b[c] = *(const float4*)&Wx[(size_t)(col0 + c) * DD + k4 * 4];
        #pragma unroll
        for (int r = 0; r < 8; ++r)
            #pragma unroll
            for (int c = 0; c < 8; ++c)
                acc[r][c] += a[r].x * b[c].x + a[r].y * b[c].y
                           + a[r].z * b[c].z + a[r].w * b[c].w;
    }

    float4 bx0 = *(const float4*)&bx[col0];
    float4 bx1 = *(const float4*)&bx[col0 + 4];
    #pragma unroll
    for (int r = 0; r < 8; ++r) {
        float4 o0, o1;
        o0.x = acc[r][0] + bx0.x; o0.y = acc[r][1] + bx0.y;
        o0.z = acc[r][2] + bx0.z; o0.w = acc[r][3] + bx0.w;
        o1.x = acc[r][4] + bx1.x; o1.y = acc[r][5] + bx1.y;
        o1.z = acc[r][6] + bx1.z; o1.w = acc[r][7] + bx1.w;
        *(float4*)&out[(size_t)(row0 + r) * HH + col0]     = o0;
        *(float4*)&out[(size_t)(row0 + r) * HH + col0 + 4] = o1;
    }
}

// ---------------- Phase 2: MFMA scan, one workgroup (4 waves) per batch -----
// R7 structure (proven: 1637us, absmax 3.9e-3): h_t (1x256) x W_h^T per step
// via mfma_f32_16x16x32_f16 with M broadcast; weights resident as 128 AGPRs
// of B-fragments; wave w owns cols [64w,64w+64): 4 N-tiles x 8 K-tiles = 32
// MFMA/wave/step; A-frags 8x ds_read_b128 (conflict-free); 1 barrier/step.
// R10 change: __syncthreads drains vmcnt(0) -> any global op inside a step
// pays full L2-ack latency serially. So (a) h stores are buffered in 16 regs
// and issued once per 16-step chunk right after a barrier (drain amortized
// 16x, and mostly complete by the time a barrier sees it); (b) xh prefetch
// chunk CH 8->16 halves the load-drain amortized cost.
__global__ __launch_bounds__(256, 1) void rnn_scan(
    const float* __restrict__ Wh, const float* __restrict__ bh,
    float* __restrict__ out)
{
    const int tid  = threadIdx.x;       // 0..255
    const int w    = tid >> 6;          // wave 0..3
    const int lane = tid & 63;
    const int g    = lane >> 4;         // k-group / owning tile 0..3
    const int c    = lane & 15;         // col within tile
    const int b    = blockIdx.x;        // batch
    const int j    = (w << 6) + lane;   // owned output unit

    __shared__ __align__(16) _Float16 hbuf[2][HH];

    // B-fragments (weights), resident for the whole scan:
    // wb[T][t] lane part = W[64w+16T+c][32t+8g .. +7] as 8 halfs
    f16x8 wb[4][8];
    #pragma unroll
    for (int T = 0; T < 4; ++T) {
        const float* wrow = Wh + (size_t)((w << 6) + (T << 4) + c) * HH;
        #pragma unroll
        for (int t = 0; t < 8; ++t) {
            const float* wp = wrow + (t << 5) + (g << 3);
            float4 v0 = *(const float4*)wp;
            float4 v1 = *(const float4*)(wp + 4);
            wb[T][t] = f16x8{(_Float16)v0.x, (_Float16)v0.y,
                             (_Float16)v0.z, (_Float16)v0.w,
                             (_Float16)v1.x, (_Float16)v1.y,
                             (_Float16)v1.z, (_Float16)v1.w};
        }
    }
    const float bhv = bh[j];
    hbuf[0][tid] = (_Float16)0.f;       // 256 threads cover all 256 units

    float* colp = out + (size_t)b * TT * HH + j;   // xh column j, stride HH

    constexpr int CH = 16;                          // chunk (timesteps)
    float xc[CH], xn[CH], hst[CH];
    #pragma unroll
    for (int i = 0; i < CH; ++i) xc[i] = colp[(size_t)i * HH];
    __syncthreads();   // zeros visible

    const int abase = (g << 4);         // byte offset of this k-group's 16B

    int cur = 0;
    const int NC = TT / CH;
    for (int cch = 0; cch < NC; ++cch) {
        // (a) flush previous chunk's h values (issued just after a barrier;
        //     they drain at the NEXT barrier ~1 step later, 1/16 amortized)
        if (cch > 0) {
            float* sp = colp + (size_t)(cch - 1) * CH * HH;
            #pragma unroll
            for (int i = 0; i < CH; ++i) sp[(size_t)i * HH] = hst[i];
        }
        // (b) prefetch next chunk's xh
        if (cch + 1 < NC) {
            const float* p = colp + (size_t)(cch + 1) * CH * HH;
            #pragma unroll
            for (int i = 0; i < CH; ++i) xn[i] = p[(size_t)i * HH];
        }
        #pragma unroll
        for (int s = 0; s < CH; ++s) {
            const char* hb = (const char*)hbuf[cur];
            // A-fragments: h[32t+8g .. +7] per K-tile t (broadcast over M rows)
            uint4 hv0 = *(const uint4*)(hb + 0 * 64 + abase);
            uint4 hv1 = *(const uint4*)(hb + 1 * 64 + abase);
            uint4 hv2 = *(const uint4*)(hb + 2 * 64 + abase);
            uint4 hv3 = *(const uint4*)(hb + 3 * 64 + abase);
            uint4 hv4 = *(const uint4*)(hb + 4 * 64 + abase);
            uint4 hv5 = *(const uint4*)(hb + 5 * 64 + abase);
            uint4 hv6 = *(const uint4*)(hb + 6 * 64 + abase);
            uint4 hv7 = *(const uint4*)(hb + 7 * 64 + abase);
            f16x8 a0 = __builtin_bit_cast(f16x8, hv0);
            f16x8 a1 = __builtin_bit_cast(f16x8, hv1);
            f16x8 a2 = __builtin_bit_cast(f16x8, hv2);
            f16x8 a3 = __builtin_bit_cast(f16x8, hv3);
            f16x8 a4 = __builtin_bit_cast(f16x8, hv4);
            f16x8 a5 = __builtin_bit_cast(f16x8, hv5);
            f16x8 a6 = __builtin_bit_cast(f16x8, hv6);
            f16x8 a7 = __builtin_bit_cast(f16x8, hv7);

            f32x4 acc0 = {0.f, 0.f, 0.f, 0.f};
            f32x4 acc1 = {0.f, 0.f, 0.f, 0.f};
            f32x4 acc2 = {0.f, 0.f, 0.f, 0.f};
            f32x4 acc3 = {0.f, 0.f, 0.f, 0.f};
#define MF(ACC, T, AV, TI) \
            ACC = __builtin_amdgcn_mfma_f32_16x16x32_f16(AV, wb[T][TI], ACC, 0, 0, 0);
            MF(acc0, 0, a0, 0) MF(acc1, 1, a0, 0) MF(acc2, 2, a0, 0) MF(acc3, 3, a0, 0)
            MF(acc0, 0, a1, 1) MF(acc1, 1, a1, 1) MF(acc2, 2, a1, 1) MF(acc3, 3, a1, 1)
            MF(acc0, 0, a2, 2) MF(acc1, 1, a2, 2) MF(acc2, 2, a2, 2) MF(acc3, 3, a2, 2)
            MF(acc0, 0, a3, 3) MF(acc1, 1, a3, 3) MF(acc2, 2, a3, 3) MF(acc3, 3, a3, 3)
            MF(acc0, 0, a4, 4) MF(acc1, 1, a4, 4) MF(acc2, 2, a4, 4) MF(acc3, 3, a4, 4)
            MF(acc0, 0, a5, 5) MF(acc1, 1, a5, 5) MF(acc2, 2, a5, 5) MF(acc3, 3, a5, 5)
            MF(acc0, 0, a6, 6) MF(acc1, 1, a6, 6) MF(acc2, 2, a6, 6) MF(acc3, 3, a6, 6)
            MF(acc0, 0, a7, 7) MF(acc1, 1, a7, 7) MF(acc2, 2, a7, 7) MF(acc3, 3, a7, 7)
#undef MF
            // lane owns tile g, col c; all C rows identical -> element 0
            float av = acc0[0];
            av = (g == 1) ? acc1[0] : av;
            av = (g == 2) ? acc2[0] : av;
            av = (g == 3) ? acc3[0] : av;

            float z  = xc[s] + bhv + av;
            float hn = tanh_fast(z);
            hst[s] = hn;                             // buffer, store later
            hbuf[cur ^ 1][j] = (_Float16)hn;         // publish for next step
            cur ^= 1;
            __syncthreads();
        }
        #pragma unroll
        for (int i = 0; i < CH; ++i) xc[i] = xn[i];
    }
    // flush final chunk
    float* sp = colp + (size_t)(NC - 1) * CH * HH;
    #pragma unroll
    for (int i = 0; i < CH; ++i) sp[(size_t)i * HH] = hst[i];
}

extern "C" void kernel_launch(void* const* d_in, const int* in_sizes, int n_in,
                              void* d_out, int out_size, void* d_ws, size_t ws_size,
                              hipStream_t stream) {
    const float* inp = (const float*)d_in[0];   // [B,T,D]
    const float* Wx  = (const float*)d_in[1];   // [H,D]
    const float* bx  = (const float*)d_in[2];   // [H]
    const float* Wh  = (const float*)d_in[3];   // [H,H]
    const float* bh  = (const float*)d_in[4];   // [H]
    float* out = (float*)d_out;                 // [B,T,H]

    dim3 g1(BB * TT / 128, HH / 128);
    x2h_gemm<<<g1, 256, 0, stream>>>(inp, Wx, bx, out);
    rnn_scan<<<BB, 256, 0, stream>>>(Wh, bh, out);
}

// Round 11
// 1663.881 us; speedup vs baseline: 1.1970x; 1.1458x over previous
//
#include <hip/hip_runtime.h>

typedef _Float16 f16x8 __attribute__((ext_vector_type(8)));
typedef float f32x4 __attribute__((ext_vector_type(4)));

#define BB 16
#define TT 4096
#define DD 128
#define HH 256

__device__ __forceinline__ float tanh_fast(float x) {
    // tanh(x) = 1 - 2/(exp(2x)+1); exact at both saturations
    float e = __expf(2.0f * x);
    return 1.0f - 2.0f * __builtin_amdgcn_rcpf(e + 1.0f);
}

// ---------------- Phase 1: xh = X @ Wx^T + bx via f16 MFMA ------------------
// M=65536 (b,t) x N=256 (h) x K=128 (d). Block: 128x128 tile, 256 thr, 4 waves
// (2x2), wave tile 64x64 = 4x4 MFMA tiles, K in 4 steps of 32. fp32 inputs
// converted to f16 during LDS staging (error ~1e-3, same class as the scan's
// fp16 weights). LDS rows padded to 136 halfs (272 B -> rows advance 4 banks,
// 16-lane row-stride reads are 2-way aliased = free). B-frag lane mapping
// (col=lane&15, k=8*(lane>>4)+m) is the R7-verified layout; A mirrors it.
__global__ __launch_bounds__(256) void x2h_mfma(
    const float* __restrict__ inp, const float* __restrict__ Wx,
    const float* __restrict__ bx, float* __restrict__ out)
{
    const int tid = threadIdx.x;
    const int mrow0 = blockIdx.x * 128;   // flattened (b,t) row base
    const int col0  = blockIdx.y * 128;   // h col base

    __shared__ __align__(16) _Float16 As[128][136];
    __shared__ __align__(16) _Float16 Bs[128][136];

    // stage: 8 iters x 256 thr x 8 elems = 128x128 each for A and B
    #pragma unroll
    for (int it = 0; it < 8; ++it) {
        int idx = it * 2048 + tid * 8;
        int r = idx >> 7, k = idx & 127;
        const float4* p = (const float4*)&inp[(size_t)(mrow0 + r) * DD + k];
        float4 v0 = p[0], v1 = p[1];
        f16x8 av = {(_Float16)v0.x, (_Float16)v0.y, (_Float16)v0.z, (_Float16)v0.w,
                    (_Float16)v1.x, (_Float16)v1.y, (_Float16)v1.z, (_Float16)v1.w};
        *(f16x8*)&As[r][k] = av;
        const float4* q = (const float4*)&Wx[(size_t)(col0 + r) * DD + k];
        float4 w0 = q[0], w1 = q[1];
        f16x8 bv = {(_Float16)w0.x, (_Float16)w0.y, (_Float16)w0.z, (_Float16)w0.w,
                    (_Float16)w1.x, (_Float16)w1.y, (_Float16)w1.z, (_Float16)w1.w};
        *(f16x8*)&Bs[r][k] = bv;
    }
    __syncthreads();

    const int w = tid >> 6, lane = tid & 63;
    const int wr = w >> 1, wc = w & 1;       // 2x2 wave grid
    const int lr = lane & 15;                // row/col within 16-tile
    const int lk = lane >> 4;                // k-subgroup (x8 halfs)

    f32x4 acc[4][4];
    #pragma unroll
    for (int i = 0; i < 4; ++i)
        #pragma unroll
        for (int j = 0; j < 4; ++j)
            acc[i][j] = f32x4{0.f, 0.f, 0.f, 0.f};

    #pragma unroll
    for (int ks = 0; ks < 4; ++ks) {
        f16x8 af[4], bf[4];
        #pragma unroll
        for (int i = 0; i < 4; ++i)
            af[i] = *(const f16x8*)&As[wr * 64 + i * 16 + lr][ks * 32 + lk * 8];
        #pragma unroll
        for (int j = 0; j < 4; ++j)
            bf[j] = *(const f16x8*)&Bs[wc * 64 + j * 16 + lr][ks * 32 + lk * 8];
        #pragma unroll
        for (int i = 0; i < 4; ++i)
            #pragma unroll
            for (int j = 0; j < 4; ++j)
                acc[i][j] = __builtin_amdgcn_mfma_f32_16x16x32_f16(
                    af[i], bf[j], acc[i][j], 0, 0, 0);
    }

    // epilogue: C layout col=lane&15, row=(lane>>4)*4+reg (m89-verified)
    #pragma unroll
    for (int j = 0; j < 4; ++j) {
        const int col = col0 + wc * 64 + j * 16 + lr;
        const float bxv = bx[col];
        #pragma unroll
        for (int i = 0; i < 4; ++i) {
            #pragma unroll
            for (int rr = 0; rr < 4; ++rr) {
                int row = mrow0 + wr * 64 + i * 16 + lk * 4 + rr;
                out[(size_t)row * HH + col] = acc[i][j][rr] + bxv;
            }
        }
    }
}

// ---------------- Phase 2: MFMA scan, one workgroup (4 waves) per batch -----
// Exact R7 kernel (measured 1637us, absmax 3.9e-3): h_t (1x256) x W_h^T per
// step via mfma_f32_16x16x32_f16 with M broadcast; weights resident as 128
// AGPRs of B-fragments; wave w owns cols [64w,64w+64): 4 N-tiles x 8 K-tiles
// = 32 MFMA/wave/step; A-frags 8x ds_read_b128 (broadcast, conflict-free);
// 1 barrier/step. Step ~960 cyc = MFMA pipe ~620 (structural floor for f16
// at 128 MFMA/step) + ds latency ~120 + tail ~200. R10's store-buffering
// variant regressed (+108us) -> reverted.
__global__ __launch_bounds__(256, 1) void rnn_scan(
    const float* __restrict__ Wh, const float* __restrict__ bh,
    float* __restrict__ out)
{
    const int tid  = threadIdx.x;       // 0..255
    const int w    = tid >> 6;          // wave 0..3
    const int lane = tid & 63;
    const int g    = lane >> 4;         // k-group / owning tile 0..3
    const int c    = lane & 15;         // col within tile
    const int b    = blockIdx.x;        // batch
    const int j    = (w << 6) + lane;   // owned output unit

    __shared__ __align__(16) _Float16 hbuf[2][HH];

    // B-fragments (weights), resident for the whole scan:
    // wb[T][t] lane part = W[64w+16T+c][32t+8g .. +7] as 8 halfs
    f16x8 wb[4][8];
    #pragma unroll
    for (int T = 0; T < 4; ++T) {
        const float* wrow = Wh + (size_t)((w << 6) + (T << 4) + c) * HH;
        #pragma unroll
        for (int t = 0; t < 8; ++t) {
            const float* wp = wrow + (t << 5) + (g << 3);
            float4 v0 = *(const float4*)wp;
            float4 v1 = *(const float4*)(wp + 4);
            wb[T][t] = f16x8{(_Float16)v0.x, (_Float16)v0.y,
                             (_Float16)v0.z, (_Float16)v0.w,
                             (_Float16)v1.x, (_Float16)v1.y,
                             (_Float16)v1.z, (_Float16)v1.w};
        }
    }
    const float bhv = bh[j];
    hbuf[0][tid] = (_Float16)0.f;       // 256 threads cover all 256 units

    float* colp = out + (size_t)b * TT * HH + j;   // xh column j, stride HH

    constexpr int CH = 8;                           // x prefetch chunk
    float xc[CH], xn[CH];
    #pragma unroll
    for (int i = 0; i < CH; ++i) xc[i] = colp[(size_t)i * HH];
    __syncthreads();   // zeros visible

    const int abase = (g << 4);         // byte offset of this k-group's 16B

    int cur = 0;
    const int NC = TT / CH;
    for (int cch = 0; cch < NC; ++cch) {
        if (cch + 1 < NC) {
            const float* p = colp + (size_t)(cch + 1) * CH * HH;
            #pragma unroll
            for (int i = 0; i < CH; ++i) xn[i] = p[(size_t)i * HH];
        }
        float* op = colp + (size_t)cch * CH * HH;
        #pragma unroll
        for (int s = 0; s < CH; ++s) {
            const char* hb = (const char*)hbuf[cur];
            // A-fragments: h[32t+8g .. +7] per K-tile t (broadcast over M rows)
            uint4 hv0 = *(const uint4*)(hb + 0 * 64 + abase);
            uint4 hv1 = *(const uint4*)(hb + 1 * 64 + abase);
            uint4 hv2 = *(const uint4*)(hb + 2 * 64 + abase);
            uint4 hv3 = *(const uint4*)(hb + 3 * 64 + abase);
            uint4 hv4 = *(const uint4*)(hb + 4 * 64 + abase);
            uint4 hv5 = *(const uint4*)(hb + 5 * 64 + abase);
            uint4 hv6 = *(const uint4*)(hb + 6 * 64 + abase);
            uint4 hv7 = *(const uint4*)(hb + 7 * 64 + abase);
            f16x8 a0 = __builtin_bit_cast(f16x8, hv0);
            f16x8 a1 = __builtin_bit_cast(f16x8, hv1);
            f16x8 a2 = __builtin_bit_cast(f16x8, hv2);
            f16x8 a3 = __builtin_bit_cast(f16x8, hv3);
            f16x8 a4 = __builtin_bit_cast(f16x8, hv4);
            f16x8 a5 = __builtin_bit_cast(f16x8, hv5);
            f16x8 a6 = __builtin_bit_cast(f16x8, hv6);
            f16x8 a7 = __builtin_bit_cast(f16x8, hv7);

            f32x4 acc0 = {0.f, 0.f, 0.f, 0.f};
            f32x4 acc1 = {0.f, 0.f, 0.f, 0.f};
            f32x4 acc2 = {0.f, 0.f, 0.f, 0.f};
            f32x4 acc3 = {0.f, 0.f, 0.f, 0.f};
#define MF(ACC, T, AV, TI) \
            ACC = __builtin_amdgcn_mfma_f32_16x16x32_f16(AV, wb[T][TI], ACC, 0, 0, 0);
            MF(acc0, 0, a0, 0) MF(acc1, 1, a0, 0) MF(acc2, 2, a0, 0) MF(acc3, 3, a0, 0)
            MF(acc0, 0, a1, 1) MF(acc1, 1, a1, 1) MF(acc2, 2, a1, 1) MF(acc3, 3, a1, 1)
            MF(acc0, 0, a2, 2) MF(acc1, 1, a2, 2) MF(acc2, 2, a2, 2) MF(acc3, 3, a2, 2)
            MF(acc0, 0, a3, 3) MF(acc1, 1, a3, 3) MF(acc2, 2, a3, 3) MF(acc3, 3, a3, 3)
            MF(acc0, 0, a4, 4) MF(acc1, 1, a4, 4) MF(acc2, 2, a4, 4) MF(acc3, 3, a4, 4)
            MF(acc0, 0, a5, 5) MF(acc1, 1, a5, 5) MF(acc2, 2, a5, 5) MF(acc3, 3, a5, 5)
            MF(acc0, 0, a6, 6) MF(acc1, 1, a6, 6) MF(acc2, 2, a6, 6) MF(acc3, 3, a6, 6)
            MF(acc0, 0, a7, 7) MF(acc1, 1, a7, 7) MF(acc2, 2, a7, 7) MF(acc3, 3, a7, 7)
#undef MF
            // lane owns tile g, col c; all C rows identical -> element 0
            float av = acc0[0];
            av = (g == 1) ? acc1[0] : av;
            av = (g == 2) ? acc2[0] : av;
            av = (g == 3) ? acc3[0] : av;

            float z  = xc[s] + bhv + av;
            float hn = tanh_fast(z);
            op[(size_t)s * HH] = hn;                 // overwrite xh with h
            hbuf[cur ^ 1][j] = (_Float16)hn;         // publish for next step
            cur ^= 1;
            __syncthreads();
        }
        #pragma unroll
        for (int i = 0; i < CH; ++i) xc[i] = xn[i];
    }
}

extern "C" void kernel_launch(void* const* d_in, const int* in_sizes, int n_in,
                              void* d_out, int out_size, void* d_ws, size_t ws_size,
                              hipStream_t stream) {
    const float* inp = (const float*)d_in[0];   // [B,T,D]
    const float* Wx  = (const float*)d_in[1];   // [H,D]
    const float* bx  = (const float*)d_in[2];   // [H]
    const float* Wh  = (const float*)d_in[3];   // [H,H]
    const float* bh  = (const float*)d_in[4];   // [H]
    float* out = (float*)d_out;                 // [B,T,H]

    dim3 g1(BB * TT / 128, HH / 128);           // 512 x 2 blocks
    x2h_mfma<<<g1, 256, 0, stream>>>(inp, Wx, bx, out);
    rnn_scan<<<BB, 256, 0, stream>>>(Wh, bh, out);
}